// Round 1
// baseline (281.458 us; speedup 1.0000x reference)
//
#include <hip/hip_runtime.h>
#include <cmath>

#define NN 64
#define CC 256
#define TT 64
#define VV 25
#define OO 512     // 2*out_planes
#define GG 8
#define NV (NN*VV)   // 1600 elements per channel for qkv/so BN
#define STK 625      // V*V

// ---------------- kernel 1: y[n,c,v] = mean_t x[n,c,t,v] ----------------
__global__ __launch_bounds__(256) void k_mean(const float* __restrict__ x,
                                              float* __restrict__ y) {
    __shared__ float tile[TT * VV];   // 1600 floats
    int b = blockIdx.x;               // n*CC + c
    const float4* x4 = (const float4*)(x + (size_t)b * (TT * VV));
    float4* t4 = (float4*)tile;
    for (int i = threadIdx.x; i < (TT * VV) / 4; i += 256) t4[i] = x4[i];
    __syncthreads();
    if (threadIdx.x < VV) {
        float s = 0.f;
        #pragma unroll
        for (int t = 0; t < TT; ++t) s += tile[t * VV + threadIdx.x];
        y[(size_t)b * VV + threadIdx.x] = s * (1.0f / TT);
    }
}

// ---------------- kernel 2: qkv[n,o,v] = sum_c w[o,c]*y[n,c,v] ----------------
// grid = NN*8 blocks; block handles one n and a 64-wide o-chunk.
__global__ __launch_bounds__(256) void k_gemm(const float* __restrict__ y,
                                              const float* __restrict__ w,
                                              float* __restrict__ qkv) {
    __shared__ float ys[CC][VV + 1];  // [c][v], stride 26 -> conflict-free scalar reads
    int n = blockIdx.x >> 3, oc = blockIdx.x & 7;
    const float* yp = y + (size_t)n * CC * VV;
    for (int i = threadIdx.x; i < CC * VV; i += 256) ys[i / VV][i % VV] = yp[i];
    __syncthreads();
    int t = threadIdx.x;
    if (t >= 200) return;             // 200 = 8 o-slots * 25 v
    int v = t % VV, o0 = t / VV;      // o0 in 0..7
    int obase = oc * 64 + o0;
    float acc[8] = {0, 0, 0, 0, 0, 0, 0, 0};
    for (int c = 0; c < CC; c += 4) {
        float y0 = ys[c][v], y1 = ys[c + 1][v], y2 = ys[c + 2][v], y3 = ys[c + 3][v];
        #pragma unroll
        for (int u = 0; u < 8; ++u) {
            const float4 w4 = *(const float4*)&w[(size_t)(obase + u * 8) * CC + c];
            acc[u] += y0 * w4.x + y1 * w4.y + y2 * w4.z + y3 * w4.w;
        }
    }
    #pragma unroll
    for (int u = 0; u < 8; ++u)
        qkv[((size_t)n * OO + obase + u * 8) * VV + v] = acc[u];
}

// ---------------- BN stats over (n,v) for 512-channel (n,512,25) tensors ----------------
__global__ __launch_bounds__(256) void k_stats_nv(const float* __restrict__ t,
                                                  const float* __restrict__ g,
                                                  const float* __restrict__ b,
                                                  float* __restrict__ scale,
                                                  float* __restrict__ shift) {
    int ch = blockIdx.x;  // 0..511
    float s = 0.f, s2 = 0.f;
    for (int i = threadIdx.x; i < NV; i += 256) {
        int n = i / VV, v = i - n * VV;
        float val = t[((size_t)n * OO + ch) * VV + v];
        s += val; s2 += val * val;
    }
    __shared__ float ra[256], rb[256];
    ra[threadIdx.x] = s; rb[threadIdx.x] = s2;
    __syncthreads();
    for (int off = 128; off > 0; off >>= 1) {
        if (threadIdx.x < off) {
            ra[threadIdx.x] += ra[threadIdx.x + off];
            rb[threadIdx.x] += rb[threadIdx.x + off];
        }
        __syncthreads();
    }
    if (threadIdx.x == 0) {
        float m = ra[0] * (1.0f / NV);
        float var = rb[0] * (1.0f / NV) - m * m;
        float sc = g[ch] * rsqrtf(var + 1e-5f);
        scale[ch] = sc;
        shift[ch] = b[ch] - m * sc;
    }
}

// ---------------- kernel 4: per (n,g) compute qk/qr/kr into stacked ----------------
__global__ __launch_bounds__(256) void k_scores(const float* __restrict__ qkv,
                                                const float* __restrict__ rel,
                                                const float* __restrict__ qsc,
                                                const float* __restrict__ qsh,
                                                float* __restrict__ stk) {
    int n = blockIdx.x >> 3, gidx = blockIdx.x & 7;
    __shared__ float qs[16][VV], ks[16][VV], rs[32][49];
    int t = threadIdx.x;
    for (int i = t; i < 32 * VV; i += 256) {
        int c = i / VV, v = i - c * VV;
        int o = gidx * 64 + c;
        float val = qkv[((size_t)n * OO + o) * VV + v] * qsc[o] + qsh[o];
        if (c < 16) qs[c][v] = val; else ks[c - 16][v] = val;
    }
    for (int i = t; i < 32 * 49; i += 256) rs[i / 49][i % 49] = rel[i];
    __syncthreads();
    for (int ij = t; ij < STK; ij += 256) {
        int i = ij / VV, j = ij - (ij / VV) * VV;
        float aqk = 0.f, aqr = 0.f, akr = 0.f;
        #pragma unroll
        for (int c = 0; c < 16; ++c) {
            float qv = qs[c][i], kv = ks[c][j];
            aqk += qv * kv;
            aqr += qv * rs[c][i - j + 24];
            akr += kv * rs[16 + c][j - i + 24];
        }
        size_t base = (size_t)n * 24;
        stk[(base + gidx) * STK + ij]      = aqk;
        stk[(base + 8 + gidx) * STK + ij]  = aqr;
        stk[(base + 16 + gidx) * STK + ij] = akr;
    }
}

// ---------------- BN stats for stacked (24 channels x 40000) — two stage ----------------
__global__ __launch_bounds__(256) void k_stats24_a(const float* __restrict__ stk,
                                                   float* __restrict__ part) {
    int ch = blockIdx.x >> 4, chunk = blockIdx.x & 15;  // 4 n per chunk
    float s = 0.f, s2 = 0.f;
    for (int i = threadIdx.x; i < 4 * STK; i += 256) {
        int n = chunk * 4 + i / STK, r = i - (i / STK) * STK;
        float v = stk[((size_t)n * 24 + ch) * STK + r];
        s += v; s2 += v * v;
    }
    __shared__ float ra[256], rb[256];
    ra[threadIdx.x] = s; rb[threadIdx.x] = s2;
    __syncthreads();
    for (int off = 128; off > 0; off >>= 1) {
        if (threadIdx.x < off) {
            ra[threadIdx.x] += ra[threadIdx.x + off];
            rb[threadIdx.x] += rb[threadIdx.x + off];
        }
        __syncthreads();
    }
    if (threadIdx.x == 0) {
        part[(ch * 16 + chunk) * 2]     = ra[0];
        part[(ch * 16 + chunk) * 2 + 1] = rb[0];
    }
}

__global__ __launch_bounds__(64) void k_stats24_b(const float* __restrict__ part,
                                                  const float* __restrict__ g,
                                                  const float* __restrict__ b,
                                                  float* __restrict__ scale,
                                                  float* __restrict__ shift) {
    int ch = threadIdx.x;
    if (ch < 24) {
        float s = 0.f, s2 = 0.f;
        for (int k = 0; k < 16; ++k) {
            s  += part[(ch * 16 + k) * 2];
            s2 += part[(ch * 16 + k) * 2 + 1];
        }
        float m = s * (1.0f / 40000.0f);
        float var = s2 * (1.0f / 40000.0f) - m * m;
        float sc = g[ch] * rsqrtf(var + 1e-5f);
        scale[ch] = sc;
        shift[ch] = b[ch] - m * sc;
    }
}

// ---------------- kernel 6: BN+sum -> softmax -> sv/sve ----------------
__global__ __launch_bounds__(256) void k_attnout(const float* __restrict__ stk,
                                                 const float* __restrict__ qkv,
                                                 const float* __restrict__ rel,
                                                 const float* __restrict__ qsc,
                                                 const float* __restrict__ qsh,
                                                 const float* __restrict__ ssc,
                                                 const float* __restrict__ ssh,
                                                 float* __restrict__ so) {
    int n = blockIdx.x >> 3, gidx = blockIdx.x & 7;
    __shared__ float S[STK];
    __shared__ float vs[32][VV];
    __shared__ float rs[32][49];
    int t = threadIdx.x;
    const size_t sb = (size_t)n * 24 * STK;
    float sc0 = ssc[gidx],      sh0 = ssh[gidx];
    float sc1 = ssc[8 + gidx],  sh1 = ssh[8 + gidx];
    float sc2 = ssc[16 + gidx], sh2 = ssh[16 + gidx];
    for (int ij = t; ij < STK; ij += 256) {
        float a = stk[sb + (size_t)gidx * STK + ij] * sc0 + sh0;
        a += stk[sb + (size_t)(8 + gidx) * STK + ij] * sc1 + sh1;
        a += stk[sb + (size_t)(16 + gidx) * STK + ij] * sc2 + sh2;
        S[ij] = a;
    }
    for (int i = t; i < 32 * VV; i += 256) {
        int c = i / VV, v = i - (i / VV) * VV;
        int o = gidx * 64 + 32 + c;
        vs[c][v] = qkv[((size_t)n * OO + o) * VV + v] * qsc[o] + qsh[o];
    }
    for (int i = t; i < 32 * 49; i += 256) rs[i / 49][i % 49] = rel[32 * 49 + i];
    __syncthreads();
    if (t < VV) {
        int i = t;
        float m = -1e30f;
        #pragma unroll
        for (int j = 0; j < VV; ++j) m = fmaxf(m, S[i * VV + j]);
        float sum = 0.f;
        float e[VV];
        #pragma unroll
        for (int j = 0; j < VV; ++j) { e[j] = expf(S[i * VV + j] - m); sum += e[j]; }
        float inv = 1.0f / sum;
        #pragma unroll
        for (int j = 0; j < VV; ++j) S[i * VV + j] = e[j] * inv;
    }
    __syncthreads();
    for (int idx = t; idx < 32 * VV; idx += 256) {
        int c = idx / VV, i = idx - (idx / VV) * VV;
        float sv = 0.f, sve = 0.f;
        #pragma unroll
        for (int j = 0; j < VV; ++j) {
            float p = S[i * VV + j];
            sv  += p * vs[c][j];
            sve += p * rs[c][i - j + 24];
        }
        size_t o = (size_t)(gidx * 32 + c) * 2;
        so[((size_t)n * OO + o) * VV + i]     = sv;
        so[((size_t)n * OO + o + 1) * VV + i] = sve;
    }
}

// ---------------- kernel 8: out = x * (1 + sigmoid(bn(so[2p]) + bn(so[2p+1]))) ----------------
__global__ __launch_bounds__(256) void k_final(const float* __restrict__ x,
                                               const float* __restrict__ so,
                                               const float* __restrict__ osc,
                                               const float* __restrict__ osh,
                                               float* __restrict__ out) {
    int b = blockIdx.x;            // n*CC + p
    int n = b >> 8, p = b & 255;
    __shared__ float orow[VV];
    if (threadIdx.x < VV) {
        int v = threadIdx.x;
        int o0 = 2 * p, o1 = 2 * p + 1;
        float a  = so[((size_t)n * OO + o0) * VV + v] * osc[o0] + osh[o0];
        float c2 = so[((size_t)n * OO + o1) * VV + v] * osc[o1] + osh[o1];
        float z = a + c2;
        orow[v] = 1.0f + 1.0f / (1.0f + expf(-z));
    }
    __syncthreads();
    const float4* x4 = (const float4*)(x + (size_t)b * (TT * VV));
    float4* y4 = (float4*)(out + (size_t)b * (TT * VV));
    for (int wv = threadIdx.x; wv < (TT * VV) / 4; wv += 256) {
        float4 xv = x4[wv];
        int e = 4 * wv;
        int v0 = e % VV;
        float4 r;
        int v;
        v = v0;                      r.x = xv.x * orow[v];
        v = v0 + 1; if (v >= VV) v -= VV; r.y = xv.y * orow[v];
        v = v0 + 2; if (v >= VV) v -= VV; r.z = xv.z * orow[v];
        v = v0 + 3; if (v >= VV) v -= VV; r.w = xv.w * orow[v];
        y4[wv] = r;
    }
}

extern "C" void kernel_launch(void* const* d_in, const int* in_sizes, int n_in,
                              void* d_out, int out_size, void* d_ws, size_t ws_size,
                              hipStream_t stream) {
    (void)in_sizes; (void)n_in; (void)out_size; (void)ws_size;
    const float* x        = (const float*)d_in[0];
    const float* w_qkv    = (const float*)d_in[1];
    const float* relative = (const float*)d_in[2];
    const float* bn_qkv_g = (const float*)d_in[3];
    const float* bn_qkv_b = (const float*)d_in[4];
    const float* bn_sim_g = (const float*)d_in[5];
    const float* bn_sim_b = (const float*)d_in[6];
    const float* bn_out_g = (const float*)d_in[7];
    const float* bn_out_b = (const float*)d_in[8];
    float* out = (float*)d_out;

    float* ws = (float*)d_ws;
    float* w_y    = ws;                 // NN*CC*VV      = 409600
    float* w_qkvp = ws + 409600;        // NN*OO*VV      = 819200
    float* w_stk  = ws + 1228800;       // NN*24*STK     = 960000
    float* w_so   = ws + 2188800;       // NN*OO*VV      = 819200
    float* qsc    = ws + 3008000;       // 512
    float* qsh    = qsc + 512;
    float* ssc    = qsh + 512;          // 24
    float* ssh    = ssc + 24;
    float* osc    = ssh + 24;           // 512
    float* osh    = osc + 512;
    float* w_part = osh + 512;          // 24*16*2 = 768

    k_mean<<<NN * CC, 256, 0, stream>>>(x, w_y);
    k_gemm<<<NN * 8, 256, 0, stream>>>(w_y, w_qkv, w_qkvp);
    k_stats_nv<<<OO, 256, 0, stream>>>(w_qkvp, bn_qkv_g, bn_qkv_b, qsc, qsh);
    k_scores<<<NN * GG, 256, 0, stream>>>(w_qkvp, relative, qsc, qsh, w_stk);
    k_stats24_a<<<24 * 16, 256, 0, stream>>>(w_stk, w_part);
    k_stats24_b<<<1, 64, 0, stream>>>(w_part, bn_sim_g, bn_sim_b, ssc, ssh);
    k_attnout<<<NN * GG, 256, 0, stream>>>(w_stk, w_qkvp, relative, qsc, qsh, ssc, ssh, w_so);
    k_stats_nv<<<OO, 256, 0, stream>>>(w_so, bn_out_g, bn_out_b, osc, osh);
    k_final<<<NN * CC, 256, 0, stream>>>(x, w_so, osc, osh, out);
}